// Round 1
// baseline (568.870 us; speedup 1.0000x reference)
//
#include <hip/hip_runtime.h>

// ---------------------------------------------------------------------------
// BitfieldLinear: y = x @ W^T + bias, W decoded from bitfield codes + int8 resid
// Strategy: decode W -> bf16 [N,K] in ws, convert x -> bf16 [M,K] in ws,
// then m97-style bf16 MFMA GEMM (128x128 tile, BK=32, global_load_lds x16).
// ---------------------------------------------------------------------------

typedef __bf16 bf16x8 __attribute__((ext_vector_type(8)));
typedef float f32x4 __attribute__((ext_vector_type(4)));
typedef unsigned short u16x8 __attribute__((ext_vector_type(8)));

__device__ __forceinline__ unsigned short f2bf(float f) {
    union { float f; unsigned int u; } c; c.f = f;
    unsigned int u = c.u;
    u += 0x7fffu + ((u >> 16) & 1u);   // round-to-nearest-even
    return (unsigned short)(u >> 16);
}

__device__ __forceinline__ void load_lds16(const void* g, void* l) {
    __builtin_amdgcn_global_load_lds(
        (__attribute__((address_space(1))) void*)(void*)g,
        (__attribute__((address_space(3))) void*)l,
        16, 0, 0);
}

// ---------------- Kernel A: decode W into bf16 [N, K] ----------------------
__global__ void decode_w_kernel(const int* __restrict__ codes,
                                const float* __restrict__ basis,
                                const int* __restrict__ q,
                                const float* __restrict__ scales,
                                unsigned short* __restrict__ Wb, int K) {
    const int o = blockIdx.x;
    const int code = codes[o];
    const int bi = code & 0xFF;
    const float r = (float)((code >> 8) & 0xFFFF) * (1.0f / 65535.0f);
    const float s = scales[o];
    const float* brow = basis + (size_t)bi * K;
    const int*   qrow = q     + (size_t)o  * K;
    unsigned short* wrow = Wb + (size_t)o  * K;
    const float inv127 = 1.0f / 127.0f;
    for (int i = threadIdx.x * 4; i < K; i += blockDim.x * 4) {
        float4 b4 = *(const float4*)(brow + i);
        int4   q4 = *(const int4*)(qrow + i);
        ushort4 w;
        w.x = f2bf(r * b4.x + s * (float)(q4.x - 128) * inv127);
        w.y = f2bf(r * b4.y + s * (float)(q4.y - 128) * inv127);
        w.z = f2bf(r * b4.z + s * (float)(q4.z - 128) * inv127);
        w.w = f2bf(r * b4.w + s * (float)(q4.w - 128) * inv127);
        *(ushort4*)(wrow + i) = w;
    }
}

// ---------------- Kernel B: x fp32 -> bf16 ---------------------------------
__global__ void cvt_x_kernel(const float4* __restrict__ x4,
                             ushort4* __restrict__ xb4, int n4) {
    int i = blockIdx.x * blockDim.x + threadIdx.x;
    const int stride = gridDim.x * blockDim.x;
    for (; i < n4; i += stride) {
        float4 v = x4[i];
        ushort4 o;
        o.x = f2bf(v.x); o.y = f2bf(v.y); o.z = f2bf(v.z); o.w = f2bf(v.w);
        xb4[i] = o;
    }
}

// ---------------- Kernel C: bf16 GEMM, C = Xb @ Wb^T + bias ----------------
// 128x128 tile, BK=32, 256 threads = 4 waves in 2x2, each wave 64x64 (4x4 MFMA)
#define TILE_M 128
#define TILE_N 128
#define TILE_K 32

__global__ void gemm_bt_kernel(const unsigned short* __restrict__ Xb, // [M,K]
                               const unsigned short* __restrict__ Wb, // [N,K]
                               const float* __restrict__ bias,        // [N]
                               float* __restrict__ out,               // [M,N]
                               int M, int N, int K) {
    __shared__ __align__(16) unsigned short As[TILE_M * TILE_K];
    __shared__ __align__(16) unsigned short Bs[TILE_N * TILE_K];

    const int tid  = threadIdx.x;
    const int lane = tid & 63;
    const int wv   = tid >> 6;        // wave id 0..3
    const int wrow = wv >> 1;         // 0..1
    const int wcol = wv & 1;          // 0..1
    const int m0 = blockIdx.y * TILE_M;
    const int n0 = blockIdx.x * TILE_N;

    const int lr = lane & 15;         // row/col within 16-tile
    const int kg = lane >> 4;         // k-group 0..3

    f32x4 acc[4][4];
#pragma unroll
    for (int mi = 0; mi < 4; ++mi)
#pragma unroll
        for (int ni = 0; ni < 4; ++ni)
            acc[mi][ni] = (f32x4){0.f, 0.f, 0.f, 0.f};

    // Staging: tile is 128 rows x 32 cols bf16 = 8 KB = 512 chunks of 16 B.
    // 256 threads -> 2 chunks each. LDS dest offset = chunk_linear*16 bytes,
    // which is wave-uniform-base + lane*16 (required by global_load_lds).
    const int lin0 = tid, lin1 = tid + 256;
    const int ar0 = lin0 >> 2, ac0 = (lin0 & 3) * 8;
    const int ar1 = lin1 >> 2, ac1 = (lin1 & 3) * 8;

    const unsigned short* Ag0 = Xb + (size_t)(m0 + ar0) * K + ac0;
    const unsigned short* Ag1 = Xb + (size_t)(m0 + ar1) * K + ac1;
    const unsigned short* Bg0 = Wb + (size_t)(n0 + ar0) * K + ac0;
    const unsigned short* Bg1 = Wb + (size_t)(n0 + ar1) * K + ac1;

    unsigned short* Al0 = As + lin0 * 8;
    unsigned short* Al1 = As + lin1 * 8;
    unsigned short* Bl0 = Bs + lin0 * 8;
    unsigned short* Bl1 = Bs + lin1 * 8;

    for (int k0 = 0; k0 < K; k0 += TILE_K) {
        load_lds16(Ag0 + k0, Al0);
        load_lds16(Ag1 + k0, Al1);
        load_lds16(Bg0 + k0, Bl0);
        load_lds16(Bg1 + k0, Bl1);
        __syncthreads();   // compiler emits s_waitcnt vmcnt(0) before barrier

        bf16x8 af[4], bfr[4];
#pragma unroll
        for (int mi = 0; mi < 4; ++mi) {
            u16x8 raw = *(const u16x8*)(As + (wrow * 64 + mi * 16 + lr) * TILE_K + kg * 8);
            af[mi] = __builtin_bit_cast(bf16x8, raw);
        }
#pragma unroll
        for (int ni = 0; ni < 4; ++ni) {
            u16x8 raw = *(const u16x8*)(Bs + (wcol * 64 + ni * 16 + lr) * TILE_K + kg * 8);
            bfr[ni] = __builtin_bit_cast(bf16x8, raw);
        }
#pragma unroll
        for (int mi = 0; mi < 4; ++mi)
#pragma unroll
            for (int ni = 0; ni < 4; ++ni)
                acc[mi][ni] = __builtin_amdgcn_mfma_f32_16x16x32_bf16(
                    af[mi], bfr[ni], acc[mi][ni], 0, 0, 0);
        __syncthreads();
    }

    // Epilogue: C/D layout col=lane&15, row=(lane>>4)*4+reg  [m89/m91]
#pragma unroll
    for (int ni = 0; ni < 4; ++ni) {
        const int n = n0 + wcol * 64 + ni * 16 + lr;
        const float bv = bias[n];
#pragma unroll
        for (int mi = 0; mi < 4; ++mi) {
            const int mbase = m0 + wrow * 64 + mi * 16 + kg * 4;
#pragma unroll
            for (int rg = 0; rg < 4; ++rg)
                out[(size_t)(mbase + rg) * N + n] = acc[mi][ni][rg] + bv;
        }
    }
}

// ---------------------------------------------------------------------------
extern "C" void kernel_launch(void* const* d_in, const int* in_sizes, int n_in,
                              void* d_out, int out_size, void* d_ws, size_t ws_size,
                              hipStream_t stream) {
    const float* x        = (const float*)d_in[0];
    const int*   codes    = (const int*)d_in[1];
    const float* basis    = (const float*)d_in[2];
    const int*   q        = (const int*)d_in[3];
    const float* scales   = (const float*)d_in[4];
    const float* bias     = (const float*)d_in[5];
    float* out = (float*)d_out;

    const int BASIS = 256;
    const int K = in_sizes[2] / BASIS;   // D_in  (4096)
    const int N = in_sizes[1];           // D_out (4096)
    const int M = in_sizes[0] / K;       // B*S   (8192)

    unsigned short* Xb = (unsigned short*)d_ws;            // [M,K] bf16
    unsigned short* Wb = Xb + (size_t)M * K;               // [N,K] bf16

    // x fp32 -> bf16
    const int n4 = (M * K) / 4;
    cvt_x_kernel<<<4096, 256, 0, stream>>>((const float4*)x, (ushort4*)Xb, n4);

    // decode W -> bf16
    decode_w_kernel<<<N, 256, 0, stream>>>(codes, basis, q, scales, Wb, K);

    // GEMM
    dim3 grid(N / TILE_N, M / TILE_M);
    gemm_bt_kernel<<<grid, 256, 0, stream>>>(Xb, Wb, bias, out, M, N, K);
}